// Round 1
// baseline (25382.552 us; speedup 1.0000x reference)
//
#include <hip/hip_runtime.h>

// Problem constants (from reference)
#define N_USER 100000
#define N_ITEM 200000
#define N_NODE 300000   // N_USER + N_ITEM
#define DIM    64
#define N_EDGE 10000000
#define N_LAYER 3

// ---------------------------------------------------------------------------
// concat(u, i) -> cur  and  acc (= layer-0 term of the output sum)
// One thread per float4. N_USER*DIM = 6.4M is divisible by 4, so the u/i
// boundary is float4-aligned.
// ---------------------------------------------------------------------------
__global__ __launch_bounds__(256) void concat_init(
    const float* __restrict__ uE, const float* __restrict__ iE,
    float* __restrict__ cur, float* __restrict__ acc)
{
    int i = blockIdx.x * blockDim.x + threadIdx.x;    // float4 index
    const int n4 = N_NODE * DIM / 4;                  // 4.8M
    if (i >= n4) return;
    int off = i * 4;
    const int ubound = N_USER * DIM;                  // 6.4M
    const float* src = (off < ubound) ? (uE + off) : (iE + (off - ubound));
    float4 x = *(const float4*)src;
    *(float4*)(cur + off) = x;
    *(float4*)(acc + off) = x;
}

// ---------------------------------------------------------------------------
// COO SpMM, push/scatter with HW f32 atomics.
// One wave handles 64 consecutive edges:
//   - coalesced load of 64 (row,col,val) triples (one per lane)
//   - 16 inner steps: quarter-wave (16 lanes) per edge; each lane gathers a
//     float4 of cur[col] and atomic-adds 4 floats into next[row].
// ---------------------------------------------------------------------------
__global__ __launch_bounds__(256) void spmm_atomic(
    const int*   __restrict__ rows,
    const int*   __restrict__ cols,
    const float* __restrict__ vals,
    const float* __restrict__ cur,
    float*       __restrict__ next)
{
    const int lane = threadIdx.x & 63;
    const int wave = (blockIdx.x * blockDim.x + threadIdx.x) >> 6;
    const int base = wave * 64;
    if (base >= N_EDGE) return;

    int   r64 = 0, c64 = 0;
    float v64 = 0.0f;
    const int e = base + lane;
    if (e < N_EDGE) {            // E = 10M is divisible by 64; guard is safety
        r64 = rows[e];
        c64 = cols[e];
        v64 = vals[e];
    }
    const int nloc = min(64, N_EDGE - base);

    const int sub = lane >> 4;           // 0..3 : which edge of the group of 4
    const int d4  = (lane & 15) << 2;    // 0,4,...,60 : dim offset (float4)

    #pragma unroll 4
    for (int j = 0; j < 64; j += 4) {
        const int   eidx = j + sub;
        const int   r = __shfl(r64, eidx);
        const int   c = __shfl(c64, eidx);
        const float v = __shfl(v64, eidx);
        if (eidx < nloc) {
            const float4 x = *(const float4*)(cur + c * DIM + d4);
            float* dst = next + r * DIM + d4;
            unsafeAtomicAdd(dst + 0, v * x.x);   // HW global_atomic_add_f32
            unsafeAtomicAdd(dst + 1, v * x.y);
            unsafeAtomicAdd(dst + 2, v * x.z);
            unsafeAtomicAdd(dst + 3, v * x.w);
        }
    }
}

// ---------------------------------------------------------------------------
// acc += next   (residual accumulation of each layer's output)
// ---------------------------------------------------------------------------
__global__ __launch_bounds__(256) void acc_add(
    const float* __restrict__ next, float* __restrict__ acc)
{
    int i = blockIdx.x * blockDim.x + threadIdx.x;
    const int n4 = N_NODE * DIM / 4;
    if (i >= n4) return;
    int off = i * 4;
    float4 a = *(float4*)(acc + off);
    float4 b = *(const float4*)(next + off);
    a.x += b.x; a.y += b.y; a.z += b.z; a.w += b.w;
    *(float4*)(acc + off) = a;
}

extern "C" void kernel_launch(void* const* d_in, const int* in_sizes, int n_in,
                              void* d_out, int out_size, void* d_ws, size_t ws_size,
                              hipStream_t stream)
{
    const int*   rows = (const int*)  d_in[0];
    const int*   cols = (const int*)  d_in[1];
    const float* vals = (const float*)d_in[2];
    const float* uE   = (const float*)d_in[3];
    const float* iE   = (const float*)d_in[4];
    float*       acc  = (float*)d_out;

    const size_t nd = (size_t)N_NODE * DIM;          // 19.2M floats
    float* bufA = (float*)d_ws;
    float* bufB = bufA + nd;

    const int n4       = (int)(nd / 4);
    const int cpyBlks  = (n4 + 255) / 256;
    const int waves    = (N_EDGE + 63) / 64;         // 156250
    const int spmmBlks = (int)(((long long)waves * 64 + 255) / 256);

    concat_init<<<cpyBlks, 256, 0, stream>>>(uE, iE, bufA, acc);

    float* cur = bufA;
    float* nxt = bufB;
    for (int l = 0; l < N_LAYER; ++l) {
        hipMemsetAsync(nxt, 0, nd * sizeof(float), stream);
        spmm_atomic<<<spmmBlks, 256, 0, stream>>>(rows, cols, vals, cur, nxt);
        acc_add<<<cpyBlks, 256, 0, stream>>>(nxt, acc);
        float* t = cur; cur = nxt; nxt = t;
    }
}

// Round 2
// 2274.594 us; speedup vs baseline: 11.1592x; 11.1592x over previous
//
#include <hip/hip_runtime.h>

// Problem constants (from reference)
#define N_USER 100000
#define N_ITEM 200000
#define N_NODE 300000   // N_USER + N_ITEM
#define DIM    64
#define N_EDGE 10000000
#define N_LAYER 3

#define SCAN_B 256
#define NBLK_SCAN ((N_NODE + SCAN_B - 1) / SCAN_B)   // 1172

// ---------------------------------------------------------------------------
// concat(u, i) -> cur  and  acc (= layer-0 term of the output sum)
// ---------------------------------------------------------------------------
__global__ __launch_bounds__(256) void concat_init(
    const float* __restrict__ uE, const float* __restrict__ iE,
    float* __restrict__ cur, float* __restrict__ acc)
{
    int i = blockIdx.x * blockDim.x + threadIdx.x;    // float4 index
    const int n4 = N_NODE * DIM / 4;
    if (i >= n4) return;
    int off = i * 4;
    const int ubound = N_USER * DIM;
    const float* src = (off < ubound) ? (uE + off) : (iE + (off - ubound));
    float4 x = *(const float4*)src;
    *(float4*)(cur + off) = x;
    *(float4*)(acc + off) = x;
}

// ---------------------------------------------------------------------------
// CSR build: histogram -> 2-level exclusive scan -> scatter (col,val) pairs
// ---------------------------------------------------------------------------
__global__ __launch_bounds__(256) void hist_rows(
    const int* __restrict__ rows, int* __restrict__ cnt)
{
    int e = blockIdx.x * blockDim.x + threadIdx.x;
    if (e < N_EDGE) atomicAdd(&cnt[rows[e]], 1);
}

__global__ __launch_bounds__(SCAN_B) void scan1(
    const int* __restrict__ cnt, int* __restrict__ rowPtr,
    int* __restrict__ blockSum)
{
    __shared__ int s[SCAN_B];
    int i = blockIdx.x * SCAN_B + threadIdx.x;
    int x = (i < N_NODE) ? cnt[i] : 0;
    s[threadIdx.x] = x;
    __syncthreads();
    for (int off = 1; off < SCAN_B; off <<= 1) {
        int t = (threadIdx.x >= off) ? s[threadIdx.x - off] : 0;
        __syncthreads();
        s[threadIdx.x] += t;
        __syncthreads();
    }
    int incl = s[threadIdx.x];
    if (i < N_NODE) rowPtr[i] = incl - x;           // exclusive within block
    if (threadIdx.x == SCAN_B - 1) blockSum[blockIdx.x] = incl;
}

__global__ __launch_bounds__(SCAN_B) void scan2(int* __restrict__ blockSum, int nb)
{
    __shared__ int s[SCAN_B];
    int carry = 0;
    for (int base = 0; base < nb; base += SCAN_B) {
        int i = base + threadIdx.x;
        int x = (i < nb) ? blockSum[i] : 0;
        s[threadIdx.x] = x;
        __syncthreads();
        for (int off = 1; off < SCAN_B; off <<= 1) {
            int t = (threadIdx.x >= off) ? s[threadIdx.x - off] : 0;
            __syncthreads();
            s[threadIdx.x] += t;
            __syncthreads();
        }
        int incl  = s[threadIdx.x];
        int total = s[SCAN_B - 1];
        if (i < nb) blockSum[i] = incl - x + carry; // exclusive across all
        carry += total;
        __syncthreads();
    }
}

__global__ __launch_bounds__(SCAN_B) void scan3(
    int* __restrict__ rowPtr, const int* __restrict__ blockSum,
    int* __restrict__ cursor)
{
    int i = blockIdx.x * SCAN_B + threadIdx.x;
    if (i < N_NODE) {
        int v = rowPtr[i] + blockSum[blockIdx.x];
        rowPtr[i] = v;
        cursor[i] = v;
    }
    if (i == 0) rowPtr[N_NODE] = N_EDGE;
}

__global__ __launch_bounds__(256) void scatter_pairs(
    const int* __restrict__ rows, const int* __restrict__ cols,
    const float* __restrict__ vals, int* __restrict__ cursor,
    int2* __restrict__ pairs)
{
    int e = blockIdx.x * blockDim.x + threadIdx.x;
    if (e >= N_EDGE) return;
    int r = rows[e];
    int pos = atomicAdd(&cursor[r], 1);
    pairs[pos] = make_int2(cols[e], __float_as_int(vals[e]));
}

// ---------------------------------------------------------------------------
// CSR SpMM, no atomics. One wave per row; lane = dim element.
// Pairs for up to 64 edges loaded coalesced (one per lane), broadcast via
// __shfl; gather of cur[col] is a coalesced 256B wave load. acc += fused.
// ---------------------------------------------------------------------------
__global__ __launch_bounds__(256) void spmm_csr(
    const int*  __restrict__ rowPtr,
    const int2* __restrict__ pairs,
    const float* __restrict__ cur,
    float* __restrict__ nxt,
    float* __restrict__ acc)
{
    const int wid  = (blockIdx.x * blockDim.x + threadIdx.x) >> 6;  // row
    const int lane = threadIdx.x & 63;
    if (wid >= N_NODE) return;

    const int start = rowPtr[wid];
    const int end   = rowPtr[wid + 1];

    float sum = 0.0f;
    for (int e0 = start; e0 < end; e0 += 64) {
        const int n = min(64, end - e0);
        int   c = 0;
        float v = 0.0f;
        if (lane < n) {
            int2 p = pairs[e0 + lane];
            c = p.x;
            v = __int_as_float(p.y);
        }
        int j = 0;
        for (; j + 4 <= n; j += 4) {
            int   c0 = __shfl(c, j);     float v0 = __shfl(v, j);
            int   c1 = __shfl(c, j + 1); float v1 = __shfl(v, j + 1);
            int   c2 = __shfl(c, j + 2); float v2 = __shfl(v, j + 2);
            int   c3 = __shfl(c, j + 3); float v3 = __shfl(v, j + 3);
            float x0 = cur[c0 * DIM + lane];
            float x1 = cur[c1 * DIM + lane];
            float x2 = cur[c2 * DIM + lane];
            float x3 = cur[c3 * DIM + lane];
            sum += v0 * x0;
            sum += v1 * x1;
            sum += v2 * x2;
            sum += v3 * x3;
        }
        for (; j < n; ++j) {
            int   cc = __shfl(c, j);
            float vv = __shfl(v, j);
            sum += vv * cur[cc * DIM + lane];
        }
    }
    const int idx = wid * DIM + lane;
    nxt[idx] = sum;
    acc[idx] += sum;
}

// ---------------------------------------------------------------------------
// Fallback path (atomic scatter) if ws_size is too small for CSR buffers
// ---------------------------------------------------------------------------
__global__ __launch_bounds__(256) void spmm_atomic(
    const int*   __restrict__ rows,
    const int*   __restrict__ cols,
    const float* __restrict__ vals,
    const float* __restrict__ cur,
    float*       __restrict__ next)
{
    const int lane = threadIdx.x & 63;
    const int wave = (blockIdx.x * blockDim.x + threadIdx.x) >> 6;
    const int base = wave * 64;
    if (base >= N_EDGE) return;

    int   r64 = 0, c64 = 0;
    float v64 = 0.0f;
    const int e = base + lane;
    if (e < N_EDGE) { r64 = rows[e]; c64 = cols[e]; v64 = vals[e]; }
    const int nloc = min(64, N_EDGE - base);
    const int sub = lane >> 4;
    const int d4  = (lane & 15) << 2;

    #pragma unroll 4
    for (int j = 0; j < 64; j += 4) {
        const int   eidx = j + sub;
        const int   r = __shfl(r64, eidx);
        const int   c = __shfl(c64, eidx);
        const float v = __shfl(v64, eidx);
        if (eidx < nloc) {
            const float4 x = *(const float4*)(cur + c * DIM + d4);
            float* dst = next + r * DIM + d4;
            unsafeAtomicAdd(dst + 0, v * x.x);
            unsafeAtomicAdd(dst + 1, v * x.y);
            unsafeAtomicAdd(dst + 2, v * x.z);
            unsafeAtomicAdd(dst + 3, v * x.w);
        }
    }
}

__global__ __launch_bounds__(256) void acc_add(
    const float* __restrict__ next, float* __restrict__ acc)
{
    int i = blockIdx.x * blockDim.x + threadIdx.x;
    const int n4 = N_NODE * DIM / 4;
    if (i >= n4) return;
    int off = i * 4;
    float4 a = *(float4*)(acc + off);
    float4 b = *(const float4*)(next + off);
    a.x += b.x; a.y += b.y; a.z += b.z; a.w += b.w;
    *(float4*)(acc + off) = a;
}

extern "C" void kernel_launch(void* const* d_in, const int* in_sizes, int n_in,
                              void* d_out, int out_size, void* d_ws, size_t ws_size,
                              hipStream_t stream)
{
    const int*   rows = (const int*)  d_in[0];
    const int*   cols = (const int*)  d_in[1];
    const float* vals = (const float*)d_in[2];
    const float* uE   = (const float*)d_in[3];
    const float* iE   = (const float*)d_in[4];
    float*       acc  = (float*)d_out;

    const size_t nd      = (size_t)N_NODE * DIM;     // 19.2M floats
    const size_t ndBytes = nd * sizeof(float);       // 76.8 MB

    char* base = (char*)d_ws;
    float* bufA = (float*)(base);
    float* bufB = (float*)(base + ndBytes);

    const int n4       = (int)(nd / 4);
    const int cpyBlks  = (n4 + 255) / 256;
    const int edgeBlks = (N_EDGE + 255) / 256;

    // CSR workspace layout (after bufA/bufB)
    size_t off = 2 * ndBytes;
    int2* pairs = (int2*)(base + off);  off += (size_t)N_EDGE * sizeof(int2); // 80 MB
    int* rowPtr = (int*)(base + off);   off += (size_t)(N_NODE + 1) * sizeof(int);
    off = (off + 15) & ~(size_t)15;
    int* cursor = (int*)(base + off);   off += (size_t)N_NODE * sizeof(int);
    int* cnt    = (int*)(base + off);   off += (size_t)N_NODE * sizeof(int);
    int* blockSum = (int*)(base + off); off += (size_t)NBLK_SCAN * sizeof(int);
    const bool useCSR = (ws_size >= off);

    concat_init<<<cpyBlks, 256, 0, stream>>>(uE, iE, bufA, acc);

    if (useCSR) {
        // Build CSR once per call
        hipMemsetAsync(cnt, 0, (size_t)N_NODE * sizeof(int), stream);
        hist_rows<<<edgeBlks, 256, 0, stream>>>(rows, cnt);
        scan1<<<NBLK_SCAN, SCAN_B, 0, stream>>>(cnt, rowPtr, blockSum);
        scan2<<<1, SCAN_B, 0, stream>>>(blockSum, NBLK_SCAN);
        scan3<<<NBLK_SCAN, SCAN_B, 0, stream>>>(rowPtr, blockSum, cursor);
        scatter_pairs<<<edgeBlks, 256, 0, stream>>>(rows, cols, vals, cursor, pairs);

        const int spmmBlks = (int)(((size_t)N_NODE * 64 + 255) / 256);  // 75000
        float* cur = bufA;
        float* nxt = bufB;
        for (int l = 0; l < N_LAYER; ++l) {
            spmm_csr<<<spmmBlks, 256, 0, stream>>>(rowPtr, pairs, cur, nxt, acc);
            float* t = cur; cur = nxt; nxt = t;
        }
    } else {
        // Fallback: atomic scatter path
        const int waves    = (N_EDGE + 63) / 64;
        const int spmmBlks = (int)(((long long)waves * 64 + 255) / 256);
        float* cur = bufA;
        float* nxt = bufB;
        for (int l = 0; l < N_LAYER; ++l) {
            hipMemsetAsync(nxt, 0, ndBytes, stream);
            spmm_atomic<<<spmmBlks, 256, 0, stream>>>(rows, cols, vals, cur, nxt);
            acc_add<<<cpyBlks, 256, 0, stream>>>(nxt, acc);
            float* t = cur; cur = nxt; nxt = t;
        }
    }
}